// Round 6
// baseline (265.908 us; speedup 1.0000x reference)
//
#include <hip/hip_runtime.h>
#include <hip/hip_bf16.h>

typedef __attribute__((ext_vector_type(8))) short short8;
typedef __attribute__((ext_vector_type(4))) short short4v;
typedef __attribute__((ext_vector_type(4))) float f32x4;

__device__ __forceinline__ unsigned short f32_bf16(float f) {
  unsigned u = __float_as_uint(f);
  u += 0x7fffu + ((u >> 16) & 1u);  // round-to-nearest-even
  return (unsigned short)(u >> 16);
}

__device__ __forceinline__ short8 cvt8(float4 v0, float4 v1) {
  short8 f;
  f[0] = (short)f32_bf16(v0.x); f[1] = (short)f32_bf16(v0.y);
  f[2] = (short)f32_bf16(v0.z); f[3] = (short)f32_bf16(v0.w);
  f[4] = (short)f32_bf16(v1.x); f[5] = (short)f32_bf16(v1.y);
  f[6] = (short)f32_bf16(v1.z); f[7] = (short)f32_bf16(v1.w);
  return f;
}

// DPP row_shr:N add — VALU-pipe cross-lane (keeps the LDS pipe free).
// After shr8,shr4,shr2,shr1 lane 15 of each 16-lane row holds the row sum.
template <int CTRL>
__device__ __forceinline__ float dpp_add(float x) {
  int y = __builtin_amdgcn_update_dpp(0, __float_as_int(x), CTRL, 0xf, 0xf, true);
  return x + __int_as_float(y);
}
__device__ __forceinline__ float row_sum16(float x) {
  x = dpp_add<0x118>(x);  // row_shr:8
  x = dpp_add<0x114>(x);  // row_shr:4
  x = dpp_add<0x112>(x);  // row_shr:2
  x = dpp_add<0x111>(x);  // row_shr:1
  return x;               // valid in lane l15==15
}

// ---- pass 1: z (fp32) -> z_bf16 in workspace --------------------------------
__global__ __launch_bounds__(256) void cvt_bf16_kernel(const float* __restrict__ z,
                                                       unsigned short* __restrict__ zb,
                                                       int n) {
  int i = (blockIdx.x * 256 + threadIdx.x) * 8;
  if (i + 8 <= n) {
    float4 v0 = *(const float4*)(z + i);
    float4 v1 = *(const float4*)(z + i + 4);
    union { unsigned short us[8]; uint4 u4; } r;
    r.us[0] = f32_bf16(v0.x); r.us[1] = f32_bf16(v0.y);
    r.us[2] = f32_bf16(v0.z); r.us[3] = f32_bf16(v0.w);
    r.us[4] = f32_bf16(v1.x); r.us[5] = f32_bf16(v1.y);
    r.us[6] = f32_bf16(v1.z); r.us[7] = f32_bf16(v1.w);
    *(uint4*)(zb + i) = r.u4;
  }
}

// ---- pass 2: fused gather + 3-layer MLP + sigmoid ---------------------------
// 256-thread blocks, __launch_bounds__(256,2): allocator halves the arch file
// under min-waves>=3 (measured R2-R4) -> keep cap at 256 arch, occupancy from
// actual usage. Each wave: 32 edges/iter (two 16-edge m-tiles sharing every
// W1/W2 fragment read -> LDS-pipe cost per edge halves; R5 audit: LDS pipe
// ~577 cyc/16 edges was the bottleneck).
// A-frag: a[j]=A[m=lane&15][k=quad*8+j]; B-frag: b[j]=B[k=quad*8+j][n=lane&15]
// C/D:    D[row=quad*4+reg][col=lane&15]
// W1 fragments stored column-PERMUTED (ntile t, lane l15 -> col l15*4+t) so a
// lane's 4 layer-1 outputs are contiguous h1 cols -> one ds_write_b64.
// h1 swizzle: col' = (col + (row&7)*8) & 63.
// Layer-3: per-lane partials reduced with DPP row_shr adds (VALU pipe).
template <bool ZBF>
__global__ __launch_bounds__(256, 2) void lp_main(
    const float* __restrict__ zf, const unsigned short* __restrict__ zb,
    const int* __restrict__ ei,
    const float* __restrict__ W1, const float* __restrict__ b1,
    const float* __restrict__ W2, const float* __restrict__ b2,
    const float* __restrict__ W3, const float* __restrict__ b3,
    float* __restrict__ out, int nEdges) {
  __shared__ unsigned short w1l[32 * 64 * 8];               // 32 KB
  __shared__ unsigned short w2l[4 * 64 * 8];                // 4 KB
  __shared__ __align__(16) unsigned short h1s[4][16 * 64];  // 8 KB

  const int tid = threadIdx.x;
  const int wv  = tid >> 6;
  const int l   = tid & 63;
  const int l15 = l & 15;
  const int q   = l >> 4;

  // ---- stage W1 fragments into LDS (once per block, col-permuted) ----
#pragma unroll
  for (int pp = 0; pp < 8; ++pp) {
    int p = wv * 8 + pp;  // p = c*4 + t
    int c = p >> 2, t = p & 3;
    short8 f;
#pragma unroll
    for (int j = 0; j < 8; ++j)
      f[j] = (short)f32_bf16(W1[(c * 32 + q * 8 + j) * 64 + (l15 * 4 + t)]);
    *(short8*)(w1l + (p * 64 + l) * 8) = f;
  }
  // ---- stage W2 fragments into LDS (natural column order) ----
  {
    int p = tid >> 6;  // p = c*2 + t
    int c = p >> 1, t = p & 1;
    short8 f;
#pragma unroll
    for (int j = 0; j < 8; ++j)
      f[j] = (short)f32_bf16(W2[(c * 32 + q * 8 + j) * 32 + (t * 16 + l15)]);
    *(short8*)(w2l + (p * 64 + l) * 8) = f;
  }

  float bb1[4];
#pragma unroll
  for (int t = 0; t < 4; ++t) bb1[t] = b1[l15 * 4 + t];  // permuted cols
  float bb2[2];
#pragma unroll
  for (int t = 0; t < 2; ++t) bb2[t] = b2[t * 16 + l15];
  const float w3a = W3[l15], w3b = W3[16 + l15], b3v = b3[0];

  __syncthreads();

  unsigned short* h1p = h1s[wv];

  const int nIter = (nEdges + 31) >> 5;
  const int stride = gridDim.x * 4;
  int iter = blockIdx.x * 4 + wv;

  // prefetch edge indices for first iteration
  int cS0 = 0, cD0 = 0, cS1 = 0, cD1 = 0;
  if (iter < nIter) {
    int base = iter * 32;
    int e0 = base + l15;      e0 = e0 < nEdges ? e0 : nEdges - 1;
    int e1 = base + 16 + l15; e1 = e1 < nEdges ? e1 : nEdges - 1;
    cS0 = ei[e0]; cD0 = ei[nEdges + e0];
    cS1 = ei[e1]; cD1 = ei[nEdges + e1];
  }

  for (; iter < nIter; iter += stride) {
    // ---- gather both 16-edge tiles ----
    short8 a0[8], a1[8];
    if (ZBF) {
      const unsigned short* r0 = zb + (size_t)cS0 * 128;
      const unsigned short* r1 = zb + (size_t)cD0 * 128;
      const unsigned short* r2 = zb + (size_t)cS1 * 128;
      const unsigned short* r3 = zb + (size_t)cD1 * 128;
#pragma unroll
      for (int c = 0; c < 4; ++c) {
        int off = c * 32 + q * 8;
        a0[c] = *(const short8*)(r0 + off); a0[c + 4] = *(const short8*)(r1 + off);
        a1[c] = *(const short8*)(r2 + off); a1[c + 4] = *(const short8*)(r3 + off);
      }
    } else {
      const float* r0 = zf + (size_t)cS0 * 128;
      const float* r1 = zf + (size_t)cD0 * 128;
      const float* r2 = zf + (size_t)cS1 * 128;
      const float* r3 = zf + (size_t)cD1 * 128;
#pragma unroll
      for (int c = 0; c < 4; ++c) {
        int off = c * 32 + q * 8;
        a0[c]     = cvt8(*(const float4*)(r0 + off), *(const float4*)(r0 + off + 4));
        a0[c + 4] = cvt8(*(const float4*)(r1 + off), *(const float4*)(r1 + off + 4));
        a1[c]     = cvt8(*(const float4*)(r2 + off), *(const float4*)(r2 + off + 4));
        a1[c + 4] = cvt8(*(const float4*)(r3 + off), *(const float4*)(r3 + off + 4));
      }
    }

    // ---- prefetch edge indices for next iteration ----
    int nit = iter + stride;
    int nS0 = cS0, nD0 = cD0, nS1 = cS1, nD1 = cD1;
    if (nit < nIter) {
      int base = nit * 32;
      int e0 = base + l15;      e0 = e0 < nEdges ? e0 : nEdges - 1;
      int e1 = base + 16 + l15; e1 = e1 < nEdges ? e1 : nEdges - 1;
      nS0 = ei[e0]; nD0 = ei[nEdges + e0];
      nS1 = ei[e1]; nD1 = ei[nEdges + e1];
    }

    // ---- layer 1: each W1 fragment read feeds BOTH m-tiles ----
    f32x4 acc0[4], acc1[4];
#pragma unroll
    for (int t = 0; t < 4; ++t) {
      acc0[t][0] = bb1[t]; acc0[t][1] = bb1[t]; acc0[t][2] = bb1[t]; acc0[t][3] = bb1[t];
      acc1[t][0] = bb1[t]; acc1[t][1] = bb1[t]; acc1[t][2] = bb1[t]; acc1[t][3] = bb1[t];
    }
#pragma unroll
    for (int c = 0; c < 8; ++c)
#pragma unroll
      for (int t = 0; t < 4; ++t) {
        short8 wf = *(const short8*)(w1l + ((c * 4 + t) * 64 + l) * 8);
        acc0[t] = __builtin_amdgcn_mfma_f32_16x16x32_bf16(a0[c], wf, acc0[t], 0, 0, 0);
        acc1[t] = __builtin_amdgcn_mfma_f32_16x16x32_bf16(a1[c], wf, acc1[t], 0, 0, 0);
      }

    // ---- hoist W2 fragments to regs (a-regs dead now; one read per iter) ----
    short8 w2f[2][2];
#pragma unroll
    for (int c = 0; c < 2; ++c)
#pragma unroll
      for (int t = 0; t < 2; ++t)
        w2f[c][t] = *(const short8*)(w2l + ((c * 2 + t) * 64 + l) * 8);

    // ---- per tile-half epilogue ----
#pragma unroll
    for (int h = 0; h < 2; ++h) {
      f32x4* acc = h ? acc1 : acc0;
      // relu + cvt + swizzled h1 write (one ds_write_b64 per row)
#pragma unroll
      for (int r = 0; r < 4; ++r) {
        int m = q * 4 + r;
        int colb = (l15 * 4 + ((m & 7) << 3)) & 63;
        short4v v;
#pragma unroll
        for (int t = 0; t < 4; ++t) {
          float x = acc[t][r];
          x = x > 0.f ? x : 0.f;
          v[t] = (short)f32_bf16(x);
        }
        *(short4v*)(h1p + m * 64 + colb) = v;
      }

      // layer 2: [16,64] @ [64,32] + b2 (per-wave LDS, no barrier)
      int rot = (l15 & 7) << 3;
      short8 a2_0 = *(const short8*)(h1p + l15 * 64 + ((q * 8 + rot) & 63));
      short8 a2_1 = *(const short8*)(h1p + l15 * 64 + ((q * 8 + 32 + rot) & 63));

      f32x4 acc2[2];
#pragma unroll
      for (int t = 0; t < 2; ++t) {
        acc2[t][0] = bb2[t]; acc2[t][1] = bb2[t]; acc2[t][2] = bb2[t]; acc2[t][3] = bb2[t];
      }
#pragma unroll
      for (int t = 0; t < 2; ++t) {
        acc2[t] = __builtin_amdgcn_mfma_f32_16x16x32_bf16(a2_0, w2f[0][t], acc2[t], 0, 0, 0);
        acc2[t] = __builtin_amdgcn_mfma_f32_16x16x32_bf16(a2_1, w2f[1][t], acc2[t], 0, 0, 0);
      }

      // layer 3: per-lane partial, DPP row-sum (VALU pipe, no LDS)
      float p[4];
#pragma unroll
      for (int r = 0; r < 4; ++r) {
        float h0 = acc2[0][r]; h0 = h0 > 0.f ? h0 : 0.f;
        float h1v = acc2[1][r]; h1v = h1v > 0.f ? h1v : 0.f;
        p[r] = row_sum16(h0 * w3a + h1v * w3b);
      }

      if (l15 == 15) {
        int eb = iter * 32 + h * 16 + q * 4;
        float4 o;
        o.x = 1.f / (1.f + __expf(-(p[0] + b3v)));
        o.y = 1.f / (1.f + __expf(-(p[1] + b3v)));
        o.z = 1.f / (1.f + __expf(-(p[2] + b3v)));
        o.w = 1.f / (1.f + __expf(-(p[3] + b3v)));
        if (eb + 3 < nEdges) {
          *(float4*)(out + eb) = o;
        } else {
          if (eb < nEdges)     out[eb]     = o.x;
          if (eb + 1 < nEdges) out[eb + 1] = o.y;
          if (eb + 2 < nEdges) out[eb + 2] = o.z;
        }
      }
    }

    cS0 = nS0; cD0 = nD0; cS1 = nS1; cD1 = nD1;
  }
}

extern "C" void kernel_launch(void* const* d_in, const int* in_sizes, int n_in,
                              void* d_out, int out_size, void* d_ws, size_t ws_size,
                              hipStream_t stream) {
  const float* z  = (const float*)d_in[0];
  const int* ei   = (const int*)d_in[1];
  const float* W1 = (const float*)d_in[2];
  const float* b1 = (const float*)d_in[3];
  const float* W2 = (const float*)d_in[4];
  const float* b2 = (const float*)d_in[5];
  const float* W3 = (const float*)d_in[6];
  const float* b3 = (const float*)d_in[7];
  float* out = (float*)d_out;

  const int nZ = in_sizes[0];
  const int nEdges = in_sizes[1] / 2;

  const bool useWs = ws_size >= (size_t)nZ * sizeof(unsigned short);
  if (useWs) {
    unsigned short* zb = (unsigned short*)d_ws;
    int nThr = nZ / 8;
    cvt_bf16_kernel<<<(nThr + 255) / 256, 256, 0, stream>>>(z, zb, nZ);
    lp_main<true><<<1024, 256, 0, stream>>>(z, zb, ei, W1, b1, W2, b2, W3, b3, out, nEdges);
  } else {
    lp_main<false><<<1024, 256, 0, stream>>>(z, nullptr, ei, W1, b1, W2, b2, W3, b3, out, nEdges);
  }
}

// Round 7
// 197.957 us; speedup vs baseline: 1.3433x; 1.3433x over previous
//
#include <hip/hip_runtime.h>
#include <hip/hip_bf16.h>

typedef __attribute__((ext_vector_type(8))) short short8;
typedef __attribute__((ext_vector_type(4))) float f32x4;
typedef __attribute__((ext_vector_type(16))) float f32x16;

__device__ __forceinline__ unsigned short f32_bf16(float f) {
  unsigned u = __float_as_uint(f);
  u += 0x7fffu + ((u >> 16) & 1u);  // round-to-nearest-even
  return (unsigned short)(u >> 16);
}

__device__ __forceinline__ short8 cvt8(float4 v0, float4 v1) {
  short8 f;
  f[0] = (short)f32_bf16(v0.x); f[1] = (short)f32_bf16(v0.y);
  f[2] = (short)f32_bf16(v0.z); f[3] = (short)f32_bf16(v0.w);
  f[4] = (short)f32_bf16(v1.x); f[5] = (short)f32_bf16(v1.y);
  f[6] = (short)f32_bf16(v1.z); f[7] = (short)f32_bf16(v1.w);
  return f;
}

// DPP row_shr:N add — VALU-pipe cross-lane. After shr8,4,2,1 lane 15 of each
// 16-lane row holds the row sum.
template <int CTRL>
__device__ __forceinline__ float dpp_add(float x) {
  int y = __builtin_amdgcn_update_dpp(0, __float_as_int(x), CTRL, 0xf, 0xf, true);
  return x + __int_as_float(y);
}
__device__ __forceinline__ float row_sum16(float x) {
  x = dpp_add<0x118>(x);
  x = dpp_add<0x114>(x);
  x = dpp_add<0x112>(x);
  x = dpp_add<0x111>(x);
  return x;
}

// ---- pass 1: z (fp32) -> z_bf16 in workspace --------------------------------
__global__ __launch_bounds__(256) void cvt_bf16_kernel(const float* __restrict__ z,
                                                       unsigned short* __restrict__ zb,
                                                       int n) {
  int i = (blockIdx.x * 256 + threadIdx.x) * 8;
  if (i + 8 <= n) {
    float4 v0 = *(const float4*)(z + i);
    float4 v1 = *(const float4*)(z + i + 4);
    union { unsigned short us[8]; uint4 u4; } r;
    r.us[0] = f32_bf16(v0.x); r.us[1] = f32_bf16(v0.y);
    r.us[2] = f32_bf16(v0.z); r.us[3] = f32_bf16(v0.w);
    r.us[4] = f32_bf16(v1.x); r.us[5] = f32_bf16(v1.y);
    r.us[6] = f32_bf16(v1.z); r.us[7] = f32_bf16(v1.w);
    *(uint4*)(zb + i) = r.u4;
  }
}

// ---- pass 2: fused gather + 3-layer MLP + sigmoid ---------------------------
// Layer 1 on mfma_f32_32x32x16_bf16: M=32 edges, N=64 (2 n-tiles), K=256 (16
// chunks). Gathered z rows are the A operand (A[m=lane&31][k=(lane>>5)*8+j]),
// consumed per-chunk -> peak frag regs 48, total arch ~115 < the measured 128
// arch wall (R2/R3/R4/R6 all spilled above it). W1 is the B operand, re-read
// from LDS (32 ds_read_b128 per 32 edges — half of R5's per-edge cost).
// Column-slot trick: MFMA slot (ntile t, col) computes original feature
// 2*col+t, so C/D (row=(r&3)+8*(r>>2)+4*(lane>>5), col=lane&31) packs each
// lane's two per-row outputs into ONE b32 write into naturally-ordered h1.
// Layer 2 = R5's verified 16x16x32 path on two 16-edge tiles sharing one
// 16-row h1 buffer (DS ops are in-order per wave -> no barrier needed).
// Grid = 768 = exactly 3 blocks/CU (46080 B LDS) — persistent, no 4th-round
// occupancy tail (R5 measured 6.7 waves/CU vs 12 theoretical from that tail).
template <bool ZBF>
__global__ __launch_bounds__(256, 2) void lp_main(
    const float* __restrict__ zf, const unsigned short* __restrict__ zb,
    const int* __restrict__ ei,
    const float* __restrict__ W1, const float* __restrict__ b1,
    const float* __restrict__ W2, const float* __restrict__ b2,
    const float* __restrict__ W3, const float* __restrict__ b3,
    float* __restrict__ out, int nEdges) {
  __shared__ unsigned short w1l[32 * 64 * 8];               // 32 KB
  __shared__ unsigned short w2l[4 * 64 * 8];                // 4 KB
  __shared__ __align__(16) unsigned short h1s[4][16 * 72];  // 9 KB (16 rows/wave)

  const int tid = threadIdx.x;
  const int wv  = tid >> 6;
  const int l   = tid & 63;
  const int l15 = l & 15;
  const int q   = l >> 4;
  const int e32 = l & 31;   // edge-in-tile for 32x32 A/C
  const int hb  = l >> 5;   // k-half for 32x32 A/B

  // ---- stage W1 B-fragments (32x32x16): frag p = c*2 + t ----
  // slot (t, col=e32) computes original feature 2*e32 + t.
#pragma unroll
  for (int pp = 0; pp < 8; ++pp) {
    int p = wv * 8 + pp;
    int c = p >> 1, t = p & 1;
    short8 f;
#pragma unroll
    for (int j = 0; j < 8; ++j)
      f[j] = (short)f32_bf16(W1[(c * 16 + hb * 8 + j) * 64 + ((e32 << 1) | t)]);
    *(short8*)(w1l + (p * 64 + l) * 8) = f;
  }
  // ---- stage W2 B-fragments (16x16x32): frag p = c2*2 + t2, natural order ----
  {
    int c2 = wv >> 1, t2 = wv & 1;
    short8 f;
#pragma unroll
    for (int j = 0; j < 8; ++j)
      f[j] = (short)f32_bf16(W2[(c2 * 32 + q * 8 + j) * 32 + (t2 * 16 + l15)]);
    *(short8*)(w2l + (wv * 64 + l) * 8) = f;
  }

  float bb1[2];
#pragma unroll
  for (int t = 0; t < 2; ++t) bb1[t] = b1[(e32 << 1) | t];
  float bb2[2];
#pragma unroll
  for (int t = 0; t < 2; ++t) bb2[t] = b2[t * 16 + l15];
  const float w3a = W3[l15], w3b = W3[16 + l15], b3v = b3[0];

  __syncthreads();

  unsigned short* h1p = h1s[wv];
  unsigned* h1w = (unsigned*)h1p;  // dword view, row stride 36

  const int nIter = (nEdges + 31) >> 5;
  const int stride = gridDim.x * 4;
  int iter = blockIdx.x * 4 + wv;

  int cS = 0, cD = 0;
  if (iter < nIter) {
    int e = iter * 32 + e32;
    e = e < nEdges ? e : nEdges - 1;
    cS = ei[e];
    cD = ei[nEdges + e];
  }

  for (; iter < nIter; iter += stride) {
    short8 as[8], ad[8];
    if (ZBF) {
      const unsigned short* rs = zb + (size_t)cS * 128;
      const unsigned short* rd = zb + (size_t)cD * 128;
#pragma unroll
      for (int c = 0; c < 8; ++c) as[c] = *(const short8*)(rs + c * 16 + hb * 8);
#pragma unroll
      for (int c = 0; c < 4; ++c) ad[c] = *(const short8*)(rd + c * 16 + hb * 8);
    } else {
      const float* rs = zf + (size_t)cS * 128;
      const float* rd = zf + (size_t)cD * 128;
#pragma unroll
      for (int c = 0; c < 8; ++c) {
        int off = c * 16 + hb * 8;
        as[c] = cvt8(*(const float4*)(rs + off), *(const float4*)(rs + off + 4));
      }
#pragma unroll
      for (int c = 0; c < 4; ++c) {
        int off = c * 16 + hb * 8;
        ad[c] = cvt8(*(const float4*)(rd + off), *(const float4*)(rd + off + 4));
      }
    }

    // prefetch next iteration's edge indices
    int nit = iter + stride;
    int nS = cS, nD = cD;
    if (nit < nIter) {
      int e = nit * 32 + e32;
      e = e < nEdges ? e : nEdges - 1;
      nS = ei[e];
      nD = ei[nEdges + e];
    }

    // ---- layer 1: [32,256] @ [256,64], 32x32x16 ----
    f32x16 acc[2];
#pragma unroll
    for (int t = 0; t < 2; ++t)
#pragma unroll
      for (int i = 0; i < 16; ++i) acc[t][i] = bb1[t];

#pragma unroll
    for (int c = 0; c < 8; ++c) {
      short8 w0 = *(const short8*)(w1l + ((c * 2 + 0) * 64 + l) * 8);
      acc[0] = __builtin_amdgcn_mfma_f32_32x32x16_bf16(as[c], w0, acc[0], 0, 0, 0);
      short8 w1f = *(const short8*)(w1l + ((c * 2 + 1) * 64 + l) * 8);
      acc[1] = __builtin_amdgcn_mfma_f32_32x32x16_bf16(as[c], w1f, acc[1], 0, 0, 0);
    }
    __builtin_amdgcn_sched_barrier(0);  // keep ad[4..7] loads below (reg wall)
    if (ZBF) {
      const unsigned short* rd = zb + (size_t)cD * 128;
#pragma unroll
      for (int c = 4; c < 8; ++c) ad[c] = *(const short8*)(rd + c * 16 + hb * 8);
    } else {
      const float* rd = zf + (size_t)cD * 128;
#pragma unroll
      for (int c = 4; c < 8; ++c) {
        int off = c * 16 + hb * 8;
        ad[c] = cvt8(*(const float4*)(rd + off), *(const float4*)(rd + off + 4));
      }
    }
#pragma unroll
    for (int c = 0; c < 8; ++c) {
      short8 w0 = *(const short8*)(w1l + (((c + 8) * 2 + 0) * 64 + l) * 8);
      acc[0] = __builtin_amdgcn_mfma_f32_32x32x16_bf16(ad[c], w0, acc[0], 0, 0, 0);
      short8 w1f = *(const short8*)(w1l + (((c + 8) * 2 + 1) * 64 + l) * 8);
      acc[1] = __builtin_amdgcn_mfma_f32_32x32x16_bf16(ad[c], w1f, acc[1], 0, 0, 0);
    }

    // hoist W2 fragments (a-regs dead now)
    short8 w2f[2][2];
#pragma unroll
    for (int c2 = 0; c2 < 2; ++c2)
#pragma unroll
      for (int t2 = 0; t2 < 2; ++t2)
        w2f[c2][t2] = *(const short8*)(w2l + ((c2 * 2 + t2) * 64 + l) * 8);

    // ---- per 16-edge tile: h1 write -> layer2 -> layer3 -> store ----
#pragma unroll
    for (int T = 0; T < 2; ++T) {
      // relu + pack 2 feats (2*e32, 2*e32+1) -> one b32 per row-reg
#pragma unroll
      for (int rr = 0; rr < 8; ++rr) {
        int r = T * 8 + rr;
        int er = (rr & 3) + 8 * (rr >> 2) + 4 * hb;  // local row 0..15
        float v0 = acc[0][r]; v0 = v0 > 0.f ? v0 : 0.f;
        float v1 = acc[1][r]; v1 = v1 > 0.f ? v1 : 0.f;
        unsigned u = ((unsigned)f32_bf16(v1) << 16) | f32_bf16(v0);
        h1w[er * 36 + e32] = u;
      }

      // layer 2: [16,64] @ [64,32], 16x16x32 (verified R5 path)
      short8 a2_0 = *(const short8*)(h1p + l15 * 72 + q * 8);
      short8 a2_1 = *(const short8*)(h1p + l15 * 72 + 32 + q * 8);

      f32x4 acc2[2];
#pragma unroll
      for (int t2 = 0; t2 < 2; ++t2) {
        acc2[t2][0] = bb2[t2]; acc2[t2][1] = bb2[t2];
        acc2[t2][2] = bb2[t2]; acc2[t2][3] = bb2[t2];
      }
#pragma unroll
      for (int t2 = 0; t2 < 2; ++t2) {
        acc2[t2] = __builtin_amdgcn_mfma_f32_16x16x32_bf16(a2_0, w2f[0][t2], acc2[t2], 0, 0, 0);
        acc2[t2] = __builtin_amdgcn_mfma_f32_16x16x32_bf16(a2_1, w2f[1][t2], acc2[t2], 0, 0, 0);
      }

      // layer 3: per-lane partial, DPP row-sum (VALU pipe)
      float p[4];
#pragma unroll
      for (int r2 = 0; r2 < 4; ++r2) {
        float h0 = acc2[0][r2]; h0 = h0 > 0.f ? h0 : 0.f;
        float h1v = acc2[1][r2]; h1v = h1v > 0.f ? h1v : 0.f;
        p[r2] = row_sum16(h0 * w3a + h1v * w3b);
      }

      if (l15 == 15) {
        int eb = iter * 32 + T * 16 + q * 4;
        float4 o;
        o.x = 1.f / (1.f + __expf(-(p[0] + b3v)));
        o.y = 1.f / (1.f + __expf(-(p[1] + b3v)));
        o.z = 1.f / (1.f + __expf(-(p[2] + b3v)));
        o.w = 1.f / (1.f + __expf(-(p[3] + b3v)));
        if (eb + 3 < nEdges) {
          *(float4*)(out + eb) = o;
        } else {
          if (eb < nEdges)     out[eb]     = o.x;
          if (eb + 1 < nEdges) out[eb + 1] = o.y;
          if (eb + 2 < nEdges) out[eb + 2] = o.z;
        }
      }
    }

    cS = nS; cD = nD;
  }
}

extern "C" void kernel_launch(void* const* d_in, const int* in_sizes, int n_in,
                              void* d_out, int out_size, void* d_ws, size_t ws_size,
                              hipStream_t stream) {
  const float* z  = (const float*)d_in[0];
  const int* ei   = (const int*)d_in[1];
  const float* W1 = (const float*)d_in[2];
  const float* b1 = (const float*)d_in[3];
  const float* W2 = (const float*)d_in[4];
  const float* b2 = (const float*)d_in[5];
  const float* W3 = (const float*)d_in[6];
  const float* b3 = (const float*)d_in[7];
  float* out = (float*)d_out;

  const int nZ = in_sizes[0];
  const int nEdges = in_sizes[1] / 2;

  const bool useWs = ws_size >= (size_t)nZ * sizeof(unsigned short);
  if (useWs) {
    unsigned short* zb = (unsigned short*)d_ws;
    int nThr = nZ / 8;
    cvt_bf16_kernel<<<(nThr + 255) / 256, 256, 0, stream>>>(z, zb, nZ);
    lp_main<true><<<768, 256, 0, stream>>>(z, zb, ei, W1, b1, W2, b2, W3, b3, out, nEdges);
  } else {
    lp_main<false><<<768, 256, 0, stream>>>(z, nullptr, ei, W1, b1, W2, b2, W3, b3, out, nEdges);
  }
}